// Round 11
// baseline (208.288 us; speedup 1.0000x reference)
//
#include <hip/hip_runtime.h>
#include <stdint.h>

#define NB 8
#define NP 196
#define NM 2048
#define NH 768
#define NT 64
#define PPAD 224          // NP padded to multiple of 32 for MFMA K
#define NROWS (NB*NP)     // 1568

typedef __attribute__((ext_vector_type(8))) short short8;
typedef __attribute__((ext_vector_type(4))) float floatx4;
typedef __fp16 h2 __attribute__((ext_vector_type(2)));

__device__ __forceinline__ float lo2f_(uint32_t u){ union{uint32_t i; float f;} v; v.i=u<<16; return v.f; }
__device__ __forceinline__ float hi2f_(uint32_t u){ union{uint32_t i; float f;} v; v.i=u&0xffff0000u; return v.f; }
__device__ __forceinline__ uint16_t f2b_(float f){
    union{float f; uint32_t i;} v; v.f=f; uint32_t x=v.i;
    return (uint16_t)((x + 0x7fffu + ((x>>16)&1u))>>16);
}
__device__ __forceinline__ uint16_t f2h_(float f){
    union{__fp16 h; uint16_t u;} v; v.h = (__fp16)f; return v.u;
}
__device__ __forceinline__ h2 u2h2(uint32_t u){ union{uint32_t u; h2 h;} v; v.u=u; return v.h; }
__device__ __forceinline__ uint32_t h22u(h2 h){ union{h2 h; uint32_t u;} v; v.h=h; return v.u; }
__device__ __forceinline__ short8 ldfrag(const uint16_t* p){
    union{ uint4 u; short8 s; } v; v.u = *(const uint4*)p; return v.s;
}

// ---------- cvt3: fp32 -> bf16 for maps, W_map, W_final ----------
__global__ __launch_bounds__(256)
void cvt3(const float* __restrict__ s0, uint16_t* __restrict__ d0, int n0,
          const float* __restrict__ s1, uint16_t* __restrict__ d1, int n1,
          const float* __restrict__ s2, uint16_t* __restrict__ d2, int n2)
{
    long i = (long)(blockIdx.x*256 + threadIdx.x)*8;
    const float* s; uint16_t* d; long j;
    if (i < n0)                { s=s0; d=d0; j=i; }
    else if (i < (long)n0+n1)  { s=s1; d=d1; j=i-n0; }
    else                       { s=s2; d=d2; j=i-n0-n1; if (j>=n2) return; }
    float4 a = *(const float4*)(s+j);
    float4 b = *(const float4*)(s+j+4);
    uint4 w;
    w.x = (uint32_t)f2b_(a.x) | ((uint32_t)f2b_(a.y)<<16);
    w.y = (uint32_t)f2b_(a.z) | ((uint32_t)f2b_(a.w)<<16);
    w.z = (uint32_t)f2b_(b.x) | ((uint32_t)f2b_(b.y)<<16);
    w.w = (uint32_t)f2b_(b.z) | ((uint32_t)f2b_(b.w)<<16);
    *(uint4*)(d+j) = w;
}

// ---------- K1v3: [mlo_f16 | G_bf16] = fm · [Wmap;Wfin]^T ----------
// No LDS: direct-from-L2 64x64 single-wave tiles, 4x4 reg blocking, depth-2 prefetch.
__global__ __launch_bounds__(64)
void k1v3(const uint16_t* __restrict__ A, const uint16_t* __restrict__ Bcat,
          const float* __restrict__ bmap, uint16_t* __restrict__ mlof,
          uint16_t* __restrict__ gt)
{
    const int lane = threadIdx.x;
    const int quad = lane>>4, lq = lane&15;
    const int m0 = blockIdx.x*64, n0 = blockIdx.y*64;
    const uint16_t* ap[4]; const uint16_t* bp[4];
    #pragma unroll
    for (int i=0;i<4;++i){
        int r = m0 + i*16 + lq; if (r > NROWS-1) r = NROWS-1;  // clamp loads, guard stores
        ap[i] = A    + (size_t)r*NM + quad*8;
        bp[i] = Bcat + (size_t)(n0 + i*16 + lq)*NM + quad*8;
    }
    floatx4 acc[16];
    #pragma unroll
    for (int i=0;i<16;++i) acc[i] = (floatx4){0.f,0.f,0.f,0.f};

    short8 fa[2][4], fb[2][4];
    #pragma unroll
    for (int g=0; g<2; ++g)
        #pragma unroll
        for (int i=0;i<4;++i){ fa[g][i] = ldfrag(ap[i] + g*32); fb[g][i] = ldfrag(bp[i] + g*32); }

    for (int ks=0; ks<64; ++ks){
        const int cur = ks & 1;
        #pragma unroll
        for (int ms=0;ms<4;++ms)
            #pragma unroll
            for (int ns=0;ns<4;++ns)
                acc[ms*4+ns] = __builtin_amdgcn_mfma_f32_16x16x32_bf16(fa[cur][ms], fb[cur][ns], acc[ms*4+ns], 0,0,0);
        if (ks < 62){
            const int off = (ks+2)*32;
            #pragma unroll
            for (int i=0;i<4;++i){ fa[cur][i]=ldfrag(ap[i]+off); fb[cur][i]=ldfrag(bp[i]+off); }
        }
    }
    // C/D: col = n0+ns*16+lq, row = m0+ms*16+quad*4+r   (R6-verified)
    if (n0 < NH){
        #pragma unroll
        for (int ns=0;ns<4;++ns){
            const int col = n0 + ns*16 + lq;
            const float bv = bmap[col];
            #pragma unroll
            for (int ms=0;ms<4;++ms){
                floatx4 c = acc[ms*4+ns];
                const int rb = m0 + ms*16 + quad*4;
                #pragma unroll
                for (int r=0;r<4;++r){
                    const int row = rb + r;
                    if (row < NROWS) mlof[(size_t)row*NH + col] = f2h_(c[r] + bv);
                }
            }
        }
    } else {
        #pragma unroll
        for (int ns=0;ns<4;++ns){
            const int h = n0 - NH + ns*16 + lq;
            #pragma unroll
            for (int ms=0;ms<4;++ms){
                floatx4 c = acc[ms*4+ns];
                const int rb = m0 + ms*16 + quad*4;
                #pragma unroll
                for (int r=0;r<4;++r){
                    const int row = rb + r;
                    if (row < NROWS){
                        const int b = row / NP, p = row - b*NP;
                        gt[((size_t)b*NH + h)*PPAD + p] = f2b_(c[r]);
                    }
                }
            }
        }
    }
}

// ---------- K2v5: scores + softmax. Block = (b, 2 t's), 128 thr; wave owns t. ----------
// mlo f16 tiles XOR-swizzled in LDS (b128 reads); {h,w} pre-packed f16 per block;
// inner loop = pk_add_f16 + pk_max_f16 + v_dot2_f32_f16.
__global__ __launch_bounds__(128)
void k2v5(const uint16_t* __restrict__ mlof, const float* __restrict__ hid,
          const float* __restrict__ Wrect,
          float* __restrict__ attn_out, uint16_t* __restrict__ attnb)
{
    __shared__ uint16_t s_mlo[NP*64];     // 25 KB, f16, XOR-swizzled 8-elem chunks
    __shared__ uint4 s_hw[2][192];        // 6 KB: {h01,h23,w01,w23} f16 pairs, per t
    const int blk = blockIdx.x;           // b*32 + tg
    const int b = blk >> 5, tg = blk & 31;
    const int tid = threadIdx.x, w = tid >> 6, lane = tid & 63;

    // build hw tables for the block's 2 t's
    for (int e = tid; e < 2*192; e += 128){
        const int tt = (e >= 192) ? 1 : 0;
        const int c  = e - tt*192;
        const int t  = tg*2 + tt;
        float4 hv = *(const float4*)&hid[((size_t)b*NT + t)*NH + c*4];
        float4 wv = *(const float4*)&Wrect[c*4];
        uint4 pk;
        pk.x = h22u(__builtin_amdgcn_cvt_pkrtz(hv.x, hv.y));
        pk.y = h22u(__builtin_amdgcn_cvt_pkrtz(hv.z, hv.w));
        pk.z = h22u(__builtin_amdgcn_cvt_pkrtz(wv.x, wv.y));
        pk.w = h22u(__builtin_amdgcn_cvt_pkrtz(wv.z, wv.w));
        s_hw[tt][c] = pk;
    }

    int pr[4];
    #pragma unroll
    for (int pi=0; pi<4; ++pi){
        int p = pi*64 + lane; if (p > NP-1) p = NP-1;   // clamp (masked at softmax)
        pr[pi] = p;
    }

    float sc[4] = {0.f,0.f,0.f,0.f};
    const h2 z = {(__fp16)0.f, (__fp16)0.f};

    for (int ht=0; ht<12; ++ht){
        __syncthreads();                  // first iter: also guards s_hw build
        for (int u = tid; u < NP*8; u += 128){
            const int p = u >> 3, c8 = u & 7;
            const int sw = c8 ^ (p & 7);
            *(uint4*)&s_mlo[p*64 + sw*8] =
                *(const uint4*)&mlof[(size_t)(b*NP + p)*NH + ht*64 + c8*8];
        }
        __syncthreads();
        const uint4* hwb = &s_hw[w][ht*16];
        #pragma unroll 2
        for (int c8=0; c8<8; ++c8){
            const uint4 hwA = hwb[c8*2];
            const uint4 hwB = hwb[c8*2+1];
            const h2 h0=u2h2(hwA.x), h1=u2h2(hwA.y), w0v=u2h2(hwA.z), w1v=u2h2(hwA.w);
            const h2 hh2=u2h2(hwB.x), h3=u2h2(hwB.y), w2v=u2h2(hwB.z), w3v=u2h2(hwB.w);
            #pragma unroll
            for (int pi=0; pi<4; ++pi){
                const int p = pr[pi];
                const uint4 m = *(const uint4*)&s_mlo[p*64 + ((c8 ^ (p&7))*8)];
                h2 r0 = __builtin_elementwise_max((h2)(u2h2(m.x) + h0), z);
                h2 r1 = __builtin_elementwise_max((h2)(u2h2(m.y) + h1), z);
                h2 r2 = __builtin_elementwise_max((h2)(u2h2(m.z) + hh2), z);
                h2 r3 = __builtin_elementwise_max((h2)(u2h2(m.w) + h3), z);
                sc[pi] = __builtin_amdgcn_fdot2(r0, w0v, sc[pi], false);
                sc[pi] = __builtin_amdgcn_fdot2(r1, w1v, sc[pi], false);
                sc[pi] = __builtin_amdgcn_fdot2(r2, w2v, sc[pi], false);
                sc[pi] = __builtin_amdgcn_fdot2(r3, w3v, sc[pi], false);
            }
        }
    }

    // per-wave softmax over p (b_rect cancels)
    float x[4];
    #pragma unroll
    for (int i=0;i<4;++i){
        const int p = i*64 + lane;
        x[i] = (p < NP) ? sc[i] : -3.0e38f;
    }
    float mx = fmaxf(fmaxf(x[0],x[1]),fmaxf(x[2],x[3]));
    #pragma unroll
    for (int off=32; off>0; off>>=1) mx = fmaxf(mx, __shfl_xor(mx, off));
    float sum = 0.f;
    #pragma unroll
    for (int i=0;i<4;++i){
        x[i] = (i*64+lane < NP) ? __expf(x[i]-mx) : 0.f;
        sum += x[i];
    }
    #pragma unroll
    for (int off=32; off>0; off>>=1) sum += __shfl_xor(sum, off);
    const float inv = 1.f/sum;
    const int t = tg*2 + w;
    const size_t baseF = ((size_t)b*NT + t)*NP;
    const size_t baseB = ((size_t)b*NT + t)*PPAD;
    #pragma unroll
    for (int i=0;i<4;++i){
        const int p = i*64 + lane;
        const float a = x[i]*inv;
        if (p < NP)   attn_out[baseF + p] = a;
        if (p < PPAD) attnb[baseB + p] = (p < NP) ? f2b_(a) : (uint16_t)0;
    }
}

// ---------- K4: out[b,t,:] = attn[b,t,:]·G[b] + bfin + hid. Wave-tile 16x64, K=224 ----------
__global__ __launch_bounds__(64)
void k4_small(const uint16_t* __restrict__ attnb, const uint16_t* __restrict__ gt,
              const float* __restrict__ bfin, const float* __restrict__ hid,
              float* __restrict__ out)
{
    const int lane = threadIdx.x;
    const int quad = lane>>4, lq = lane&15;
    const int tt = blockIdx.x;           // t-tile (4)
    const int n0 = blockIdx.y*64;        // h-tile (12)
    const int b  = blockIdx.z;           // batch (8)
    const uint16_t* aprow = attnb + ((size_t)b*NT + tt*16 + lq)*PPAD + quad*8;
    const uint16_t* bp[4];
    #pragma unroll
    for (int i=0;i<4;++i) bp[i] = gt + ((size_t)b*NH + n0 + i*16 + lq)*PPAD + quad*8;

    floatx4 acc[4];
    #pragma unroll
    for (int i=0;i<4;++i) acc[i] = (floatx4){0.f,0.f,0.f,0.f};
    #pragma unroll
    for (int ks=0; ks<7; ++ks){
        short8 Af = ldfrag(aprow + ks*32);
        #pragma unroll
        for (int i=0;i<4;++i)
            acc[i] = __builtin_amdgcn_mfma_f32_16x16x32_bf16(Af, ldfrag(bp[i] + ks*32), acc[i], 0,0,0);
    }
    #pragma unroll
    for (int ns=0;ns<4;++ns){
        const int col = n0 + ns*16 + lq;
        const float bv = bfin[col];
        floatx4 c = acc[ns];
        #pragma unroll
        for (int r=0;r<4;++r){
            const int row = b*NT + tt*16 + quad*4 + r;
            const size_t idx = (size_t)row*NH + col;
            out[idx] = c[r] + bv + hid[idx];
        }
    }
}

// =================== fallback (R5-proven fp32 path) ===================
__global__ __launch_bounds__(256)
void k1_map(const float* __restrict__ fm, const float* __restrict__ Wmap,
            const float* __restrict__ bmap, float* __restrict__ mlo)
{
    __shared__ float s_fm[8][NM];
    const int row0 = blockIdx.x*8;
    for (int i=threadIdx.x; i<8*NM; i+=256){
        int r=i>>11, k=i&2047;
        s_fm[r][k] = fm[(size_t)(row0+r)*NM + k];
    }
    __syncthreads();
    #pragma unroll
    for (int it=0; it<3; ++it){
        int c = threadIdx.x + it*256;
        float acc[8];
        #pragma unroll
        for(int r=0;r<8;++r) acc[r]=0.f;
        const float* wr = Wmap + (size_t)c*NM;
        for (int k=0;k<NM;k+=4){
            float4 w4 = *(const float4*)(wr + k);
            #pragma unroll
            for(int r=0;r<8;++r){
                acc[r]=fmaf(w4.x,s_fm[r][k+0],acc[r]);
                acc[r]=fmaf(w4.y,s_fm[r][k+1],acc[r]);
                acc[r]=fmaf(w4.z,s_fm[r][k+2],acc[r]);
                acc[r]=fmaf(w4.w,s_fm[r][k+3],acc[r]);
            }
        }
        float bb = bmap[c];
        for(int r=0;r<8;++r) mlo[(size_t)(row0+r)*NH + c] = acc[r]+bb;
    }
}

__global__ __launch_bounds__(256)
void k2_scores_f(const float* __restrict__ mlo, const float* __restrict__ hid,
                 const float* __restrict__ Wrect, const float* __restrict__ brect,
                 float* __restrict__ attn_out)
{
    const int b    = blockIdx.x >> 4;
    const int tg   = blockIdx.x & 15;
    const int wave = threadIdx.x >> 6;
    const int lane = threadIdx.x & 63;
    const int t    = tg*4 + wave;
    float hv[12], wv[12];
    #pragma unroll
    for (int j=0;j<12;++j){
        int h = lane + 64*j;
        hv[j] = hid[(size_t)(b*NT+t)*NH + h];
        wv[j] = Wrect[h];
    }
    __shared__ float s_sc[4][NP];
    for (int p=0;p<NP;++p){
        const float* mr = mlo + ((size_t)b*NP + p)*NH;
        float acc = 0.f;
        #pragma unroll
        for (int j=0;j<12;++j){
            float v = fmaxf(mr[lane+64*j] + hv[j], 0.f);
            acc = fmaf(v,wv[j],acc);
        }
        #pragma unroll
        for (int off=32; off>0; off>>=1) acc += __shfl_down(acc,off);
        if (lane==0) s_sc[wave][p] = acc;
    }
    __syncthreads();
    float x[4]; int pidx[4];
    #pragma unroll
    for (int i=0;i<4;++i){
        int p = lane + 64*i; pidx[i]=p;
        x[i] = (p<NP) ? s_sc[wave][p] : -3.0e38f;
    }
    float mx = fmaxf(fmaxf(x[0],x[1]),fmaxf(x[2],x[3]));
    #pragma unroll
    for (int off=32; off>0; off>>=1) mx = fmaxf(mx,__shfl_xor(mx,off));
    float sum=0.f;
    #pragma unroll
    for (int i=0;i<4;++i){ x[i] = (pidx[i]<NP) ? __expf(x[i]-mx) : 0.f; sum += x[i]; }
    #pragma unroll
    for (int off=32; off>0; off>>=1) sum += __shfl_xor(sum,off);
    const float inv = 1.f/sum;
    const size_t base = (size_t)(b*NT+t)*NP;
    #pragma unroll
    for (int i=0;i<4;++i) if (pidx[i]<NP) attn_out[base+pidx[i]] = x[i]*inv;
}

__global__ __launch_bounds__(256)
void k3_ctx(const float* __restrict__ attn, const float* __restrict__ fm,
            float* __restrict__ ctx)
{
    const int b  = blockIdx.x >> 4;
    const int tg = blockIdx.x & 15;
    __shared__ float s_a[4][NP];
    for (int i=threadIdx.x; i<4*NP; i+=256){
        int tt=i/NP, p=i-tt*NP;
        s_a[tt][p] = attn[(size_t)(b*NT + tg*4+tt)*NP + p];
    }
    __syncthreads();
    const int m0 = threadIdx.x*8;
    float acc[4][8];
    #pragma unroll
    for(int tt=0;tt<4;++tt)
        #pragma unroll
        for(int i=0;i<8;++i) acc[tt][i]=0.f;
    const float* fb = fm + (size_t)b*NP*NM + m0;
    for (int p=0;p<NP;++p){
        float4 u0 = *(const float4*)(fb + (size_t)p*NM);
        float4 u1 = *(const float4*)(fb + (size_t)p*NM + 4);
        float f[8] = {u0.x,u0.y,u0.z,u0.w,u1.x,u1.y,u1.z,u1.w};
        #pragma unroll
        for(int tt=0;tt<4;++tt){
            float a = s_a[tt][p];
            #pragma unroll
            for(int i=0;i<8;++i) acc[tt][i] = fmaf(a,f[i],acc[tt][i]);
        }
    }
    #pragma unroll
    for(int tt=0;tt<4;++tt){
        float* cr = ctx + (size_t)(b*NT + tg*4+tt)*NM + m0;
        #pragma unroll
        for(int i=0;i<8;++i) cr[i]=acc[tt][i];
    }
}

__global__ __launch_bounds__(256)
void k4_final(const float* __restrict__ ctx, const float* __restrict__ Wfin,
              const float* __restrict__ bfin, const float* __restrict__ hid,
              float* __restrict__ out)
{
    __shared__ float s_c[8][NM];
    const int row0 = blockIdx.x*8;
    for (int i=threadIdx.x; i<8*NM; i+=256){
        int r=i>>11, k=i&2047;
        s_c[r][k] = ctx[(size_t)(row0+r)*NM + k];
    }
    __syncthreads();
    #pragma unroll
    for (int it=0; it<3; ++it){
        int c = threadIdx.x + it*256;
        float acc[8];
        #pragma unroll
        for(int r=0;r<8;++r) acc[r]=0.f;
        const float* wr = Wfin + (size_t)c*NM;
        for (int k=0;k<NM;k+=4){
            float4 w4 = *(const float4*)(wr + k);
            #pragma unroll
            for(int r=0;r<8;++r){
                acc[r]=fmaf(w4.x,s_c[r][k+0],acc[r]);
                acc[r]=fmaf(w4.y,s_c[r][k+1],acc[r]);
                acc[r]=fmaf(w4.z,s_c[r][k+2],acc[r]);
                acc[r]=fmaf(w4.w,s_c[r][k+3],acc[r]);
            }
        }
        float bb = bfin[c];
        for(int r=0;r<8;++r)
            out[(size_t)(row0+r)*NH + c] = acc[r] + bb + hid[(size_t)(row0+r)*NH + c];
    }
}

extern "C" void kernel_launch(void* const* d_in, const int* in_sizes, int n_in,
                              void* d_out, int out_size, void* d_ws, size_t ws_size,
                              hipStream_t stream)
{
    const float* maps  = (const float*)d_in[0];
    const float* hid   = (const float*)d_in[1];
    const float* Wmap  = (const float*)d_in[2];
    const float* bmap  = (const float*)d_in[3];
    const float* Wfin  = (const float*)d_in[4];
    const float* bfin  = (const float*)d_in[5];
    const float* Wrect = (const float*)d_in[6];
    const float* brect = (const float*)d_in[7];

    float* out_ptr  = (float*)d_out;                  // (B,T,H) fp32
    float* attn_out = out_ptr + (size_t)NB*NT*NH;     // (B,T,P) fp32

    const int    FME    = NB*NP*NM;                   // 3,211,264
    const int    WE     = NH*NM;                      // 1,572,864
    const size_t fmb_b  = (size_t)FME*2;
    const size_t w_b    = (size_t)WE*2;
    const size_t mlo_b  = (size_t)NROWS*NH*2;         // f16 now
    const size_t gt_b   = (size_t)NB*NH*PPAD*2;
    const size_t atb_b  = (size_t)NB*NT*PPAD*2;
    const size_t need   = fmb_b + 2*w_b + mlo_b + gt_b + atb_b;  // ~17.3 MiB

    if (ws_size >= need) {
        uint16_t* fmb   = (uint16_t*)d_ws;
        uint16_t* wcat  = (uint16_t*)((char*)d_ws + fmb_b);          // [Wmap;Wfin] 1536x2048 bf16
        uint16_t* wfinb = wcat + (size_t)WE;
        uint16_t* mlof  = (uint16_t*)((char*)d_ws + fmb_b + 2*w_b);  // f16 [1568][768]
        uint16_t* gt    = mlof + (size_t)NROWS*NH;
        uint16_t* attnb = gt   + (size_t)NB*NH*PPAD;

        const int total8 = (FME + 2*WE)/8;
        hipLaunchKernelGGL(cvt3, dim3(total8/256), dim3(256), 0, stream,
                           maps, fmb, FME, Wmap, wcat, WE, Wfin, wfinb, WE);
        hipLaunchKernelGGL(k1v3, dim3(25,24), dim3(64), 0, stream,
                           fmb, wcat, bmap, mlof, gt);
        hipLaunchKernelGGL(k2v5, dim3(NB*(NT/2)), dim3(128), 0, stream,
                           mlof, hid, Wrect, attn_out, attnb);
        hipLaunchKernelGGL(k4_small, dim3(4,12,NB), dim3(64), 0, stream,
                           attnb, gt, bfin, hid, out_ptr);
    } else {
        // R5-proven fp32 fallback
        float* mlo = (float*)d_ws;
        float* ctx = mlo + (size_t)NB*NP*NH;
        hipLaunchKernelGGL(k1_map,     dim3(NB*NP/8),   dim3(256), 0, stream, maps, Wmap, bmap, mlo);
        hipLaunchKernelGGL(k2_scores_f,dim3(NB*(NT/4)), dim3(256), 0, stream, mlo, hid, Wrect, brect, attn_out);
        hipLaunchKernelGGL(k3_ctx,     dim3(NB*(NT/4)), dim3(256), 0, stream, attn_out, maps, ctx);
        hipLaunchKernelGGL(k4_final,   dim3(NB*NT/8),   dim3(256), 0, stream, ctx, Wfin, bfin, hid, out_ptr);
    }
}

// Round 12
// 136.735 us; speedup vs baseline: 1.5233x; 1.5233x over previous
//
#include <hip/hip_runtime.h>
#include <stdint.h>

#define NB 8
#define NP 196
#define NM 2048
#define NH 768
#define NT 64
#define PPAD 224          // NP padded for MFMA-K / coalesced p
#define NROWS (NB*NP)     // 1568
#define HC 16             // h-chunks in k2a
#define HCL 48            // h per chunk (16*48 = 768)

typedef __attribute__((ext_vector_type(8))) short short8;
typedef __attribute__((ext_vector_type(4))) float floatx4;
typedef __fp16 h2 __attribute__((ext_vector_type(2)));

__device__ __forceinline__ uint16_t f2b_(float f){
    union{float f; uint32_t i;} v; v.f=f; uint32_t x=v.i;
    return (uint16_t)((x + 0x7fffu + ((x>>16)&1u))>>16);
}
__device__ __forceinline__ uint16_t f2h_(float f){
    union{__fp16 h; uint16_t u;} v; v.h = (__fp16)f; return v.u;
}
__device__ __forceinline__ h2 u2h2(uint32_t u){ union{uint32_t u; h2 h;} v; v.u=u; return v.h; }
__device__ __forceinline__ short8 ldsfrag(const uint16_t* p){
    union{ uint4 u; short8 s; } v; v.u = *(const uint4*)p; return v.s;
}

// ---------- cvt3: fp32 -> bf16 for maps, W_map, W_final ----------
__global__ __launch_bounds__(256)
void cvt3(const float* __restrict__ s0, uint16_t* __restrict__ d0, int n0,
          const float* __restrict__ s1, uint16_t* __restrict__ d1, int n1,
          const float* __restrict__ s2, uint16_t* __restrict__ d2, int n2)
{
    long i = (long)(blockIdx.x*256 + threadIdx.x)*8;
    const float* s; uint16_t* d; long j;
    if (i < n0)                { s=s0; d=d0; j=i; }
    else if (i < (long)n0+n1)  { s=s1; d=d1; j=i-n0; }
    else                       { s=s2; d=d2; j=i-n0-n1; if (j>=n2) return; }
    float4 a = *(const float4*)(s+j);
    float4 b = *(const float4*)(s+j+4);
    uint4 w;
    w.x = (uint32_t)f2b_(a.x) | ((uint32_t)f2b_(a.y)<<16);
    w.y = (uint32_t)f2b_(a.z) | ((uint32_t)f2b_(a.w)<<16);
    w.z = (uint32_t)f2b_(b.x) | ((uint32_t)f2b_(b.y)<<16);
    w.w = (uint32_t)f2b_(b.z) | ((uint32_t)f2b_(b.w)<<16);
    *(uint4*)(d+j) = w;
}

// ---------- K1 (LDS-tiled MFMA, R9-proven): [mloT_f16 | G_bf16] = fm · [Wmap;Wfin]^T ----------
// 64x64 block tile, BK=64, 256 thr (4 waves, each 32x32). Grid (25, 24).
#define LSTR 72           // LDS row stride (pad 64->72: b128 ~2-way max)
__global__ __launch_bounds__(256)
void k1_tiled(const uint16_t* __restrict__ A, const uint16_t* __restrict__ Bcat,
              const float* __restrict__ bmap, uint16_t* __restrict__ mloT,
              uint16_t* __restrict__ gt)
{
    __shared__ uint16_t sA[64*LSTR];
    __shared__ uint16_t sB[64*LSTR];
    const int tid  = threadIdx.x;
    const int wv   = tid >> 6, lane = tid & 63;
    const int quad = lane >> 4, lq = lane & 15;
    const int m0 = blockIdx.x*64, n0 = blockIdx.y*64;

    const int r0 = tid >> 3, q0 = tid & 7;
    const int r1 = r0 + 32;
    int gar0 = m0 + r0; if (gar0 >= NROWS) gar0 = NROWS-1;
    int gar1 = m0 + r1; if (gar1 >= NROWS) gar1 = NROWS-1;
    const uint16_t* pa0 = A + (size_t)gar0*NM + q0*8;
    const uint16_t* pa1 = A + (size_t)gar1*NM + q0*8;
    const uint16_t* pb0 = Bcat + (size_t)(n0 + r0)*NM + q0*8;
    const uint16_t* pb1 = Bcat + (size_t)(n0 + r1)*NM + q0*8;
    uint16_t* la0 = &sA[r0*LSTR + q0*8];
    uint16_t* la1 = &sA[r1*LSTR + q0*8];
    uint16_t* lb0 = &sB[r0*LSTR + q0*8];
    uint16_t* lb1 = &sB[r1*LSTR + q0*8];

    const int msub = (wv & 1)*32, nsub = (wv >> 1)*32;

    floatx4 acc[2][2];
    #pragma unroll
    for (int i=0;i<2;++i)
        #pragma unroll
        for (int j=0;j<2;++j) acc[i][j] = (floatx4){0.f,0.f,0.f,0.f};

    uint4 va0 = *(const uint4*)pa0, va1 = *(const uint4*)pa1;
    uint4 vb0 = *(const uint4*)pb0, vb1 = *(const uint4*)pb1;

    for (int ks=0; ks<32; ++ks){
        *(uint4*)la0 = va0; *(uint4*)la1 = va1;
        *(uint4*)lb0 = vb0; *(uint4*)lb1 = vb1;
        __syncthreads();
        if (ks < 31){
            const int off = (ks+1)*64;
            va0 = *(const uint4*)(pa0 + off);
            va1 = *(const uint4*)(pa1 + off);
            vb0 = *(const uint4*)(pb0 + off);
            vb1 = *(const uint4*)(pb1 + off);
        }
        #pragma unroll
        for (int kk=0; kk<2; ++kk){
            short8 af[2], bf[2];
            #pragma unroll
            for (int mt=0;mt<2;++mt)
                af[mt] = ldsfrag(&sA[(msub + mt*16 + lq)*LSTR + kk*32 + quad*8]);
            #pragma unroll
            for (int nt=0;nt<2;++nt)
                bf[nt] = ldsfrag(&sB[(nsub + nt*16 + lq)*LSTR + kk*32 + quad*8]);
            #pragma unroll
            for (int mt=0;mt<2;++mt)
                #pragma unroll
                for (int nt=0;nt<2;++nt)
                    acc[mt][nt] = __builtin_amdgcn_mfma_f32_16x16x32_bf16(af[mt], bf[nt], acc[mt][nt], 0,0,0);
        }
        __syncthreads();
    }

    // epilogue. C/D: local col = nsub+nt*16+lq, local row = msub+mt*16+quad*4+r
    if (n0 < NH){
        // mloT[b][col][p] f16 (transposed, PPAD stride) — same scatter as gt
        #pragma unroll
        for (int nt=0;nt<2;++nt){
            const int col = n0 + nsub + nt*16 + lq;
            const float bv = bmap[col];
            #pragma unroll
            for (int mt=0;mt<2;++mt){
                floatx4 c = acc[mt][nt];
                const int rb = m0 + msub + mt*16 + quad*4;
                #pragma unroll
                for (int r=0;r<4;++r){
                    const int row = rb + r;
                    if (row < NROWS){
                        const int b = row / NP, p = row - b*NP;
                        mloT[((size_t)b*NH + col)*PPAD + p] = f2h_(c[r] + bv);
                    }
                }
            }
        }
    } else {
        #pragma unroll
        for (int nt=0;nt<2;++nt){
            const int h = n0 - NH + nsub + nt*16 + lq;
            #pragma unroll
            for (int mt=0;mt<2;++mt){
                floatx4 c = acc[mt][nt];
                const int rb = m0 + msub + mt*16 + quad*4;
                #pragma unroll
                for (int r=0;r<4;++r){
                    const int row = rb + r;
                    if (row < NROWS){
                        const int b = row / NP, p = row - b*NP;
                        gt[((size_t)b*NH + h)*PPAD + p] = f2b_(c[r]);
                    }
                }
            }
        }
    }
}

// ---------- K2a: partial scores, no LDS. Wave = (slot, 8 t's); lanes = p pairs ----------
// partial[hc][b][t][p] = sum_{h in chunk} relu(mloT[b][h][p] + hid[b][t][h]) * Wrect[h]
__global__ __launch_bounds__(256)
void k2a(const uint16_t* __restrict__ mloT, const float* __restrict__ hid,
         const float* __restrict__ Wrect, float* __restrict__ partial)
{
    const int hcv = blockIdx.x;        // 0..15
    const int tgp = blockIdx.y;        // 0..3
    const int b   = blockIdx.z;        // 0..7
    const int tid = threadIdx.x;
    const int w   = tid >> 6;
    const int L   = tid & 63;
    const int slot = w & 1;            // 0: p 0..127, 1: p 128..223
    const int tg   = tgp*2 + (w>>1);   // 0..7
    const int t0   = tg*8;
    const int Lc   = (slot && L > 47) ? 47 : L;    // clamp (dup writes, same value)
    const int p    = slot*128 + 2*Lc;

    float acc[8][2];
    #pragma unroll
    for (int i=0;i<8;++i){ acc[i][0]=0.f; acc[i][1]=0.f; }

    const uint16_t* mp = mloT + (size_t)b*NH*PPAD + p;
    const float*    hb = hid + ((size_t)b*NT + t0)*NH;
    const int h0 = hcv*HCL;

    #pragma unroll 4
    for (int hh=0; hh<HCL; ++hh){
        const int h = h0 + hh;
        const uint32_t m = *(const uint32_t*)(mp + (size_t)h*PPAD);
        const h2 mh = u2h2(m);
        const float m0f = (float)mh.x;
        const float m1f = (float)mh.y;
        const float wvv = Wrect[h];                   // uniform -> SGPR
        #pragma unroll
        for (int ti=0; ti<8; ++ti){
            const float hv = hb[(size_t)ti*NH + h];   // uniform -> SGPR
            acc[ti][0] = fmaf(fmaxf(m0f+hv, 0.f), wvv, acc[ti][0]);
            acc[ti][1] = fmaf(fmaxf(m1f+hv, 0.f), wvv, acc[ti][1]);
        }
    }
    #pragma unroll
    for (int ti=0; ti<8; ++ti){
        float2 v = make_float2(acc[ti][0], acc[ti][1]);
        *(float2*)&partial[(((size_t)hcv*NB + b)*NT + t0+ti)*PPAD + p] = v;
    }
}

// ---------- K2b: reduce partials + softmax per (b,t) ----------
__global__ __launch_bounds__(256)
void k2b(const float* __restrict__ partial, float* __restrict__ attn_out,
         uint16_t* __restrict__ attnb)
{
    const int bt = blockIdx.x;         // b*64 + t
    const int tid = threadIdx.x;
    const int lane = tid & 63, wv = tid >> 6;
    __shared__ float s_red[8];

    float s = 0.f;
    if (tid < PPAD){
        #pragma unroll
        for (int hcv=0; hcv<HC; ++hcv)
            s += partial[(((size_t)hcv*NB*NT) + bt)*PPAD + tid];
    }
    float v = (tid < NP) ? s : -3.0e38f;
    #pragma unroll
    for (int off=32; off>0; off>>=1) v = fmaxf(v, __shfl_xor(v, off));
    if (lane == 0) s_red[wv] = v;
    __syncthreads();
    const float mx = fmaxf(fmaxf(s_red[0], s_red[1]), fmaxf(s_red[2], s_red[3]));
    float e = (tid < NP) ? __expf(s - mx) : 0.f;
    float r = e;
    #pragma unroll
    for (int off=32; off>0; off>>=1) r += __shfl_xor(r, off);
    if (lane == 0) s_red[4 + wv] = r;
    __syncthreads();
    const float inv = 1.f / (s_red[4] + s_red[5] + s_red[6] + s_red[7]);
    const float a = e * inv;
    if (tid < NP)   attn_out[(size_t)bt*NP + tid] = a;
    if (tid < PPAD) attnb[(size_t)bt*PPAD + tid] = (tid < NP) ? f2b_(a) : (uint16_t)0;
}

// ---------- K4: out[b,t,:] = attn[b,t,:]·G[b] + bfin + hid. Wave-tile 16x64, K=224 ----------
__global__ __launch_bounds__(64)
void k4_small(const uint16_t* __restrict__ attnb, const uint16_t* __restrict__ gt,
              const float* __restrict__ bfin, const float* __restrict__ hid,
              float* __restrict__ out)
{
    const int lane = threadIdx.x;
    const int quad = lane>>4, lq = lane&15;
    const int tt = blockIdx.x;           // t-tile (4)
    const int n0 = blockIdx.y*64;        // h-tile (12)
    const int b  = blockIdx.z;           // batch (8)
    const uint16_t* aprow = attnb + ((size_t)b*NT + tt*16 + lq)*PPAD + quad*8;
    const uint16_t* bp[4];
    #pragma unroll
    for (int i=0;i<4;++i) bp[i] = gt + ((size_t)b*NH + n0 + i*16 + lq)*PPAD + quad*8;

    floatx4 acc[4];
    #pragma unroll
    for (int i=0;i<4;++i) acc[i] = (floatx4){0.f,0.f,0.f,0.f};
    #pragma unroll
    for (int ks=0; ks<7; ++ks){
        short8 Af = ldsfrag(aprow + ks*32);
        #pragma unroll
        for (int i=0;i<4;++i)
            acc[i] = __builtin_amdgcn_mfma_f32_16x16x32_bf16(Af, ldsfrag(bp[i] + ks*32), acc[i], 0,0,0);
    }
    #pragma unroll
    for (int ns=0;ns<4;++ns){
        const int col = n0 + ns*16 + lq;
        const float bv = bfin[col];
        floatx4 c = acc[ns];
        #pragma unroll
        for (int r=0;r<4;++r){
            const int row = b*NT + tt*16 + quad*4 + r;
            const size_t idx = (size_t)row*NH + col;
            out[idx] = c[r] + bv + hid[idx];
        }
    }
}

// =================== fallback (R5-proven fp32 path) ===================
__global__ __launch_bounds__(256)
void k1_map(const float* __restrict__ fm, const float* __restrict__ Wmap,
            const float* __restrict__ bmap, float* __restrict__ mlo)
{
    __shared__ float s_fm[8][NM];
    const int row0 = blockIdx.x*8;
    for (int i=threadIdx.x; i<8*NM; i+=256){
        int r=i>>11, k=i&2047;
        s_fm[r][k] = fm[(size_t)(row0+r)*NM + k];
    }
    __syncthreads();
    #pragma unroll
    for (int it=0; it<3; ++it){
        int c = threadIdx.x + it*256;
        float acc[8];
        #pragma unroll
        for(int r=0;r<8;++r) acc[r]=0.f;
        const float* wr = Wmap + (size_t)c*NM;
        for (int k=0;k<NM;k+=4){
            float4 w4 = *(const float4*)(wr + k);
            #pragma unroll
            for(int r=0;r<8;++r){
                acc[r]=fmaf(w4.x,s_fm[r][k+0],acc[r]);
                acc[r]=fmaf(w4.y,s_fm[r][k+1],acc[r]);
                acc[r]=fmaf(w4.z,s_fm[r][k+2],acc[r]);
                acc[r]=fmaf(w4.w,s_fm[r][k+3],acc[r]);
            }
        }
        float bb = bmap[c];
        for(int r=0;r<8;++r) mlo[(size_t)(row0+r)*NH + c] = acc[r]+bb;
    }
}

__global__ __launch_bounds__(256)
void k2_scores_f(const float* __restrict__ mlo, const float* __restrict__ hid,
                 const float* __restrict__ Wrect, const float* __restrict__ brect,
                 float* __restrict__ attn_out)
{
    const int b    = blockIdx.x >> 4;
    const int tg   = blockIdx.x & 15;
    const int wave = threadIdx.x >> 6;
    const int lane = threadIdx.x & 63;
    const int t    = tg*4 + wave;
    float hv[12], wv[12];
    #pragma unroll
    for (int j=0;j<12;++j){
        int h = lane + 64*j;
        hv[j] = hid[(size_t)(b*NT+t)*NH + h];
        wv[j] = Wrect[h];
    }
    __shared__ float s_sc[4][NP];
    for (int p=0;p<NP;++p){
        const float* mr = mlo + ((size_t)b*NP + p)*NH;
        float acc = 0.f;
        #pragma unroll
        for (int j=0;j<12;++j){
            float v = fmaxf(mr[lane+64*j] + hv[j], 0.f);
            acc = fmaf(v,wv[j],acc);
        }
        #pragma unroll
        for (int off=32; off>0; off>>=1) acc += __shfl_down(acc,off);
        if (lane==0) s_sc[wave][p] = acc;
    }
    __syncthreads();
    float x[4]; int pidx[4];
    #pragma unroll
    for (int i=0;i<4;++i){
        int p = lane + 64*i; pidx[i]=p;
        x[i] = (p<NP) ? s_sc[wave][p] : -3.0e38f;
    }
    float mx = fmaxf(fmaxf(x[0],x[1]),fmaxf(x[2],x[3]));
    #pragma unroll
    for (int off=32; off>0; off>>=1) mx = fmaxf(mx,__shfl_xor(mx,off));
    float sum=0.f;
    #pragma unroll
    for (int i=0;i<4;++i){ x[i] = (pidx[i]<NP) ? __expf(x[i]-mx) : 0.f; sum += x[i]; }
    #pragma unroll
    for (int off=32; off>0; off>>=1) sum += __shfl_xor(sum,off);
    const float inv = 1.f/sum;
    const size_t base = (size_t)(b*NT+t)*NP;
    #pragma unroll
    for (int i=0;i<4;++i) if (pidx[i]<NP) attn_out[base+pidx[i]] = x[i]*inv;
}

__global__ __launch_bounds__(256)
void k3_ctx(const float* __restrict__ attn, const float* __restrict__ fm,
            float* __restrict__ ctx)
{
    const int b  = blockIdx.x >> 4;
    const int tg = blockIdx.x & 15;
    __shared__ float s_a[4][NP];
    for (int i=threadIdx.x; i<4*NP; i+=256){
        int tt=i/NP, p=i-tt*NP;
        s_a[tt][p] = attn[(size_t)(b*NT + tg*4+tt)*NP + p];
    }
    __syncthreads();
    const int m0 = threadIdx.x*8;
    float acc[4][8];
    #pragma unroll
    for(int tt=0;tt<4;++tt)
        #pragma unroll
        for(int i=0;i<8;++i) acc[tt][i]=0.f;
    const float* fb = fm + (size_t)b*NP*NM + m0;
    for (int p=0;p<NP;++p){
        float4 u0 = *(const float4*)(fb + (size_t)p*NM);
        float4 u1 = *(const float4*)(fb + (size_t)p*NM + 4);
        float f[8] = {u0.x,u0.y,u0.z,u0.w,u1.x,u1.y,u1.z,u1.w};
        #pragma unroll
        for(int tt=0;tt<4;++tt){
            float a = s_a[tt][p];
            #pragma unroll
            for(int i=0;i<8;++i) acc[tt][i] = fmaf(a,f[i],acc[tt][i]);
        }
    }
    #pragma unroll
    for(int tt=0;tt<4;++tt){
        float* cr = ctx + (size_t)(b*NT + tg*4+tt)*NM + m0;
        #pragma unroll
        for(int i=0;i<8;++i) cr[i]=acc[tt][i];
    }
}

__global__ __launch_bounds__(256)
void k4_final(const float* __restrict__ ctx, const float* __restrict__ Wfin,
              const float* __restrict__ bfin, const float* __restrict__ hid,
              float* __restrict__ out)
{
    __shared__ float s_c[8][NM];
    const int row0 = blockIdx.x*8;
    for (int i=threadIdx.x; i<8*NM; i+=256){
        int r=i>>11, k=i&2047;
        s_c[r][k] = ctx[(size_t)(row0+r)*NM + k];
    }
    __syncthreads();
    #pragma unroll
    for (int it=0; it<3; ++it){
        int c = threadIdx.x + it*256;
        float acc[8];
        #pragma unroll
        for(int r=0;r<8;++r) acc[r]=0.f;
        const float* wr = Wfin + (size_t)c*NM;
        for (int k=0;k<NM;k+=4){
            float4 w4 = *(const float4*)(wr + k);
            #pragma unroll
            for(int r=0;r<8;++r){
                acc[r]=fmaf(w4.x,s_c[r][k+0],acc[r]);
                acc[r]=fmaf(w4.y,s_c[r][k+1],acc[r]);
                acc[r]=fmaf(w4.z,s_c[r][k+2],acc[r]);
                acc[r]=fmaf(w4.w,s_c[r][k+3],acc[r]);
            }
        }
        float bb = bfin[c];
        for(int r=0;r<8;++r)
            out[(size_t)(row0+r)*NH + c] = acc[r] + bb + hid[(size_t)(row0+r)*NH + c];
    }
}

extern "C" void kernel_launch(void* const* d_in, const int* in_sizes, int n_in,
                              void* d_out, int out_size, void* d_ws, size_t ws_size,
                              hipStream_t stream)
{
    const float* maps  = (const float*)d_in[0];
    const float* hid   = (const float*)d_in[1];
    const float* Wmap  = (const float*)d_in[2];
    const float* bmap  = (const float*)d_in[3];
    const float* Wfin  = (const float*)d_in[4];
    const float* bfin  = (const float*)d_in[5];
    const float* Wrect = (const float*)d_in[6];
    const float* brect = (const float*)d_in[7];

    float* out_ptr  = (float*)d_out;                  // (B,T,H) fp32
    float* attn_out = out_ptr + (size_t)NB*NT*NH;     // (B,T,P) fp32

    const int    FME    = NB*NP*NM;                   // 3,211,264
    const int    WE     = NH*NM;                      // 1,572,864
    const size_t fmb_b  = (size_t)FME*2;              // 6,422,528
    const size_t w_b    = (size_t)WE*2;               // 3,145,728 each
    const size_t mloT_b = (size_t)NB*NH*PPAD*2;       // 2,752,512
    const size_t gt_b   = (size_t)NB*NH*PPAD*2;       // 2,752,512
    const size_t atb_b  = (size_t)NB*NT*PPAD*2;       //   229,376
    const size_t need   = fmb_b + 2*w_b + mloT_b + gt_b + atb_b;  // ~17.6 MiB
    // partial (HC*NB*NT*PPAD*4 = 7.34 MB) aliases fmb+wcat (12.7 MB), dead after k1.

    if (ws_size >= need) {
        uint16_t* fmb   = (uint16_t*)d_ws;
        uint16_t* wcat  = (uint16_t*)((char*)d_ws + fmb_b);          // [Wmap;Wfin] bf16
        uint16_t* wfinb = wcat + (size_t)WE;
        uint16_t* mloT  = (uint16_t*)((char*)d_ws + fmb_b + 2*w_b);  // f16 [b][h][224]
        uint16_t* gt    = mloT + (size_t)NB*NH*PPAD;                 // bf16 [b][h][224]
        uint16_t* attnb = gt   + (size_t)NB*NH*PPAD;
        float*    partial = (float*)d_ws;                            // alias (post-k1)

        const int total8 = (FME + 2*WE)/8;
        hipLaunchKernelGGL(cvt3, dim3(total8/256), dim3(256), 0, stream,
                           maps, fmb, FME, Wmap, wcat, WE, Wfin, wfinb, WE);
        hipLaunchKernelGGL(k1_tiled, dim3(25,24), dim3(256), 0, stream,
                           fmb, wcat, bmap, mloT, gt);
        hipLaunchKernelGGL(k2a, dim3(HC,4,NB), dim3(256), 0, stream,
                           mloT, hid, Wrect, partial);
        hipLaunchKernelGGL(k2b, dim3(NB*NT), dim3(256), 0, stream,
                           partial, attn_out, attnb);
        hipLaunchKernelGGL(k4_small, dim3(4,12,NB), dim3(64), 0, stream,
                           attnb, gt, bfin, hid, out_ptr);
    } else {
        // R5-proven fp32 fallback
        float* mlo = (float*)d_ws;
        float* ctx = mlo + (size_t)NB*NP*NH;
        hipLaunchKernelGGL(k1_map,     dim3(NB*NP/8),   dim3(256), 0, stream, maps, Wmap, bmap, mlo);
        hipLaunchKernelGGL(k2_scores_f,dim3(NB*(NT/4)), dim3(256), 0, stream, mlo, hid, Wrect, brect, attn_out);
        hipLaunchKernelGGL(k3_ctx,     dim3(NB*(NT/4)), dim3(256), 0, stream, attn_out, maps, ctx);
        hipLaunchKernelGGL(k4_final,   dim3(NB*NT/8),   dim3(256), 0, stream, ctx, Wfin, bfin, hid, out_ptr);
    }
}